// Round 1
// baseline (1380.421 us; speedup 1.0000x reference)
//
#include <hip/hip_runtime.h>
#include <hip/hip_bf16.h>

// B=32, NL=13, L=1024, D=768, VQ_VOCAB=320
// out[b][d] = sum_l w[b][l] * feat[b][12][l][d]
// w per reference's _run_weights (mean of run-means over valid prefix).

#define BATCH 32
#define NL 13
#define LQ 1024
#define DIM 768

// ---------------- Phase A: per-batch run weights ----------------
// one block per batch, 256 threads, 4 positions per thread
__global__ __launch_bounds__(256) void weights_kernel(
    const int* __restrict__ vq,     // (B, L, 2) int32
    const int* __restrict__ lens,   // (B,) int32
    float* __restrict__ w)          // (B, L) float32 out (workspace)
{
    const int b = blockIdx.x;
    const int t = threadIdx.x;
    const int len = lens[b];

    // pack (2 x int32) pair into one 64-bit value for equality compare
    const long long* vqb = reinterpret_cast<const long long*>(vq) + (size_t)b * LQ;

    __shared__ int runlen[LQ];
    __shared__ int waveSums[4];

    // zero run-length histogram
    runlen[t]       = 0;
    runlen[t + 256] = 0;
    runlen[t + 512] = 0;
    runlen[t + 768] = 0;

    const int i0 = t * 4;
    long long c0 = vqb[i0 + 0];
    long long c1 = vqb[i0 + 1];
    long long c2 = vqb[i0 + 2];
    long long c3 = vqb[i0 + 3];
    long long prev = (i0 == 0) ? 0LL : vqb[i0 - 1];

    // boundary bits (boundary requires valid; position 0 is always boundary if valid)
    int b0 = (i0 == 0) ? (0 < len) : ((i0 + 0 < len) && (c0 != prev));
    int b1 = (i0 + 1 < len) && (c1 != c0);
    int b2 = (i0 + 2 < len) && (c2 != c1);
    int b3 = (i0 + 3 < len) && (c3 != c2);

    // inclusive scan within thread
    int s0 = b0;
    int s1 = s0 + b1;
    int s2 = s1 + b2;
    int s3 = s2 + b3;
    const int mySum = s3;

    // wave-level inclusive scan of per-thread sums (wave = 64 lanes)
    const int lane = t & 63;
    const int wid  = t >> 6;
    int incl = mySum;
    #pragma unroll
    for (int off = 1; off < 64; off <<= 1) {
        int n = __shfl_up(incl, off);
        if (lane >= off) incl += n;
    }
    if (lane == 63) waveSums[wid] = incl;
    __syncthreads();

    int waveOff = 0;
    #pragma unroll
    for (int ww = 0; ww < 4; ++ww) {
        int v = waveSums[ww];
        if (ww < wid) waveOff += v;
    }
    const int total = waveSums[0] + waveSums[1] + waveSums[2] + waveSums[3];

    const int base = waveOff + (incl - mySum); // exclusive prefix for this thread
    // segment ids (cumsum(boundary) - 1, clipped)
    int g0 = min(max(base + s0 - 1, 0), LQ - 1);
    int g1 = min(max(base + s1 - 1, 0), LQ - 1);
    int g2 = min(max(base + s2 - 1, 0), LQ - 1);
    int g3 = min(max(base + s3 - 1, 0), LQ - 1);

    // run-length histogram over valid positions
    if (i0 + 0 < len) atomicAdd(&runlen[g0], 1);
    if (i0 + 1 < len) atomicAdd(&runlen[g1], 1);
    if (i0 + 2 < len) atomicAdd(&runlen[g2], 1);
    if (i0 + 3 < len) atomicAdd(&runlen[g3], 1);
    __syncthreads();

    const float nr = (float)total;
    float* wb = w + (size_t)b * LQ;
    wb[i0 + 0] = (i0 + 0 < len) ? 1.0f / (nr * (float)max(runlen[g0], 1)) : 0.0f;
    wb[i0 + 1] = (i0 + 1 < len) ? 1.0f / (nr * (float)max(runlen[g1], 1)) : 0.0f;
    wb[i0 + 2] = (i0 + 2 < len) ? 1.0f / (nr * (float)max(runlen[g2], 1)) : 0.0f;
    wb[i0 + 3] = (i0 + 3 < len) ? 1.0f / (nr * (float)max(runlen[g3], 1)) : 0.0f;
}

// ---------------- Phase B: weighted pooling over L ----------------
// grid (B, 16 chunks of 64 rows), 192 threads; thread t owns float4 column t
// (192 * 4 = 768 = DIM). Streams 64 rows of the LAST layer; atomicAdd to out.
#define CHUNKS 16
#define ROWS_PER_CHUNK (LQ / CHUNKS)  // 64

__global__ __launch_bounds__(192) void pool_kernel(
    const float* __restrict__ feat,   // (B, NL, L, D) float32
    const float* __restrict__ w,      // (B, L)
    float* __restrict__ out)          // (B, D)
{
    const int b = blockIdx.x;
    const int c = blockIdx.y;
    const int t = threadIdx.x;
    const int l0 = c * ROWS_PER_CHUNK;

    __shared__ float ws[ROWS_PER_CHUNK];
    if (t < ROWS_PER_CHUNK) ws[t] = w[(size_t)b * LQ + l0 + t];
    __syncthreads();

    // base of last layer (index NL-1) for this batch/chunk, as float4
    const size_t off = (((size_t)b * NL + (NL - 1)) * LQ + l0) * DIM;
    const float4* base = reinterpret_cast<const float4*>(feat + off) + t; // row stride 192 float4

    float4 a0 = make_float4(0.f, 0.f, 0.f, 0.f);
    float4 a1 = make_float4(0.f, 0.f, 0.f, 0.f);
    float4 a2 = make_float4(0.f, 0.f, 0.f, 0.f);
    float4 a3 = make_float4(0.f, 0.f, 0.f, 0.f);

    #pragma unroll
    for (int l = 0; l < ROWS_PER_CHUNK; l += 4) {
        float4 v0 = base[(size_t)(l + 0) * 192];
        float4 v1 = base[(size_t)(l + 1) * 192];
        float4 v2 = base[(size_t)(l + 2) * 192];
        float4 v3 = base[(size_t)(l + 3) * 192];
        float w0 = ws[l + 0], w1 = ws[l + 1], w2 = ws[l + 2], w3 = ws[l + 3];
        a0.x = fmaf(w0, v0.x, a0.x); a0.y = fmaf(w0, v0.y, a0.y);
        a0.z = fmaf(w0, v0.z, a0.z); a0.w = fmaf(w0, v0.w, a0.w);
        a1.x = fmaf(w1, v1.x, a1.x); a1.y = fmaf(w1, v1.y, a1.y);
        a1.z = fmaf(w1, v1.z, a1.z); a1.w = fmaf(w1, v1.w, a1.w);
        a2.x = fmaf(w2, v2.x, a2.x); a2.y = fmaf(w2, v2.y, a2.y);
        a2.z = fmaf(w2, v2.z, a2.z); a2.w = fmaf(w2, v2.w, a2.w);
        a3.x = fmaf(w3, v3.x, a3.x); a3.y = fmaf(w3, v3.y, a3.y);
        a3.z = fmaf(w3, v3.z, a3.z); a3.w = fmaf(w3, v3.w, a3.w);
    }

    float4 acc;
    acc.x = (a0.x + a1.x) + (a2.x + a3.x);
    acc.y = (a0.y + a1.y) + (a2.y + a3.y);
    acc.z = (a0.z + a1.z) + (a2.z + a3.z);
    acc.w = (a0.w + a1.w) + (a2.w + a3.w);

    float* o = out + (size_t)b * DIM + t * 4;
    atomicAdd(o + 0, acc.x);
    atomicAdd(o + 1, acc.y);
    atomicAdd(o + 2, acc.z);
    atomicAdd(o + 3, acc.w);
}

extern "C" void kernel_launch(void* const* d_in, const int* in_sizes, int n_in,
                              void* d_out, int out_size, void* d_ws, size_t ws_size,
                              hipStream_t stream) {
    const float* feat = (const float*)d_in[0];   // (32,13,1024,768) fp32
    const int*   lens = (const int*)d_in[1];     // (32,) int
    const int*   vq   = (const int*)d_in[2];     // (32,1024,2) int
    float* out = (float*)d_out;                  // (32,768) fp32
    float* w   = (float*)d_ws;                   // (32,1024) fp32 scratch

    // harness poisons d_out with 0xAA before every replay — zero it
    hipMemsetAsync(d_out, 0, (size_t)out_size * sizeof(float), stream);

    weights_kernel<<<dim3(BATCH), dim3(256), 0, stream>>>(vq, lens, w);
    pool_kernel<<<dim3(BATCH, CHUNKS), dim3(192), 0, stream>>>(feat, w, out);
}